// Round 2
// baseline (140.984 us; speedup 1.0000x reference)
//
#include <hip/hip_runtime.h>
#include <hip/hip_bf16.h>
#include <math.h>

#define BB  8
#define HH  512
#define WW  512
#define HID 32
#define KK  25

#define TS 16          // output tile (16x16)
#define GT 18          // guidance tile with 1-px halo
#define GP 20          // g_lds row stride (floats)
#define FT 20          // flow tile with 2-px halo
#define FP 21          // f_lds row stride (floats)

typedef __attribute__((ext_vector_type(8))) short  short8;
typedef __attribute__((ext_vector_type(4))) float  float4v;

#define MFMA16(a, b, c) __builtin_amdgcn_mfma_f32_16x16x32_bf16((a), (b), (c), 0, 0, 0)

static __device__ __forceinline__ ushort f2bf(float f) {
    __hip_bfloat16 h = __float2bfloat16(f);   // RNE
    return *reinterpret_cast<ushort*>(&h);
}
static __device__ __forceinline__ float bf2f(ushort u) {
    __hip_bfloat16 h;
    *reinterpret_cast<ushort*>(&h) = u;
    return __bfloat162float(h);
}
static __device__ __forceinline__ void split_bf(float f, ushort& hi, ushort& lo) {
    hi = f2bf(f);
    lo = f2bf(f - bf2f(hi));
}

__global__ __launch_bounds__(256)
void temporal_refine_kernel(const float* __restrict__ v0,   // [B,2,H,W] flow
                            const float* __restrict__ v2,   // [B,2,H,W]
                            const float* __restrict__ w1,   // [32,3,3,3] -> [32][27]
                            const float* __restrict__ b1,   // [32]
                            const float* __restrict__ w2,   // [50,32,1,1] -> [50][32]
                            const float* __restrict__ b2,   // [50]
                            float* __restrict__ out)        // [B,2,H,W]
{
    __shared__ float g_lds[3][GT][GP];                       // guidance fb0, fb1, w
    __shared__ float f_lds[2][FT][FP];                       // flow (halo 2)
    __shared__ __attribute__((aligned(16))) ushort h_s[4][2][16][40]; // per-wave bounce: [wave][hi/lo][col][oc pad40]

    const int bx0 = blockIdx.x * TS;
    const int by0 = blockIdx.y * TS;
    const int b   = blockIdx.z;
    const int tid = threadIdx.x;
    const int w   = tid >> 6;       // wave 0..3
    const int L   = tid & 63;       // lane
    const int c   = L & 15;         // MFMA col (pixel within 16-px group)
    const int q   = L >> 4;         // MFMA k/row group 0..3

    const float* v0b = v0 + (size_t)b * 2 * HH * WW;
    const float* v2b = v2 + (size_t)b * 2 * HH * WW;

    // ================= stage guidance tile (halo 1) =================
    for (int i = tid; i < GT * GT; i += 256) {
        const int ly = i / GT, lx = i - ly * GT;
        const int y = by0 - 1 + ly, x = bx0 - 1 + lx;
        float fb0 = 0.f, fb1 = 0.f, wv = 0.f;
        if (y >= 0 && y < HH && x >= 0 && x < WW) {
            const float f0 = v0b[y * WW + x];
            const float f1 = v0b[HH * WW + y * WW + x];
            const float sgx = (-1.0f + x * (2.0f / (WW - 1))) + f0 * (2.0f / WW);
            const float sgy = (-1.0f + y * (2.0f / (HH - 1))) + f1 * (2.0f / HH);
            const float ixf = (sgx + 1.0f) * (0.5f * (WW - 1));
            const float iyf = (sgy + 1.0f) * (0.5f * (HH - 1));
            const float x0f = floorf(ixf), y0f = floorf(iyf);
            const int   x0  = (int)x0f,   y0i = (int)y0f;
            const float wx1 = ixf - x0f, wx0 = 1.0f - wx1;
            const float wy1 = iyf - y0f, wy0 = 1.0f - wy1;
            float s0 = 0.f, s1 = 0.f;
            #pragma unroll
            for (int cy = 0; cy < 2; ++cy) {
                const int yy = y0i + cy;
                const float wy = cy ? wy1 : wy0;
                if (yy >= 0 && yy < HH) {
                    #pragma unroll
                    for (int cx = 0; cx < 2; ++cx) {
                        const int xx = x0 + cx;
                        if (xx >= 0 && xx < WW) {
                            const float wgt = wy * (cx ? wx1 : wx0);
                            const int idx = yy * WW + xx;
                            s0 = fmaf(wgt, v2b[idx], s0);
                            s1 = fmaf(wgt, v2b[HH * WW + idx], s1);
                        }
                    }
                }
            }
            fb0 = f0 + s0;
            fb1 = f1 + s1;
            wv  = __expf(-sqrtf(fmaf(fb0, fb0, fb1 * fb1)));
        }
        g_lds[0][ly][lx] = fb0;
        g_lds[1][ly][lx] = fb1;
        g_lds[2][ly][lx] = wv;
    }

    // ================= stage flow tile (halo 2) =================
    for (int i = tid; i < FT * FT; i += 256) {
        const int ly = i / FT, lx = i - ly * FT;
        const int y = by0 - 2 + ly, x = bx0 - 2 + lx;
        float f0 = 0.f, f1 = 0.f;
        if (y >= 0 && y < HH && x >= 0 && x < WW) {
            f0 = v0b[y * WW + x];
            f1 = v0b[HH * WW + y * WW + x];
        }
        f_lds[0][ly][lx] = f0;
        f_lds[1][ly][lx] = f1;
    }

    // ================= per-lane weight fragments (split hi/lo bf16) ==========
    // conv1 A: [32 oc x 27 k], K padded to 32. A frag: row = c (+16*t), k = 8q+i.
    short8 a1h[2], a1l[2];
    #pragma unroll
    for (int t = 0; t < 2; ++t) {
        #pragma unroll
        for (int i = 0; i < 8; ++i) {
            const int k = 8 * q + i;
            const float f = (k < 27) ? w1[(16 * t + c) * 27 + k] : 0.f;
            ushort hi, lo; split_bf(f, hi, lo);
            a1h[t][i] = (short)hi; a1l[t][i] = (short)lo;
        }
    }
    // conv2 A: [50 oc x 32 k] padded to 64 rows.
    short8 a2h[4], a2l[4];
    #pragma unroll
    for (int mt = 0; mt < 4; ++mt) {
        const int row = 16 * mt + c;
        #pragma unroll
        for (int i = 0; i < 8; ++i) {
            const int k = 8 * q + i;
            const float f = (row < 50) ? w2[row * 32 + k] : 0.f;
            ushort hi, lo; split_bf(f, hi, lo);
            a2h[mt][i] = (short)hi; a2l[mt][i] = (short)lo;
        }
    }
    // biases at C-layout positions: row = 16*tile + 4q + reg
    float b1v[8];
    #pragma unroll
    for (int t = 0; t < 2; ++t)
        #pragma unroll
        for (int r = 0; r < 4; ++r)
            b1v[t * 4 + r] = b1[16 * t + 4 * q + r];
    float b2v[16];
    int   offv[16];
    int   chmask = 0;
    #pragma unroll
    for (int mt = 0; mt < 4; ++mt) {
        #pragma unroll
        for (int r = 0; r < 4; ++r) {
            const int j = mt * 4 + r;
            const int row = 16 * mt + 4 * q + r;
            if (row < 50) {
                const int ch = (row >= 25) ? 1 : 0;
                const int k = row - 25 * ch;
                const int dy = k / 5, dx = k - dy * 5;
                b2v[j]  = b2[row];
                offv[j] = ch * (FT * FP) + dy * FP + dx;
                chmask |= ch << j;
            } else {
                b2v[j] = 0.f;
                offv[j] = -1;
            }
        }
    }
    // conv1 B gather offsets: k = 8q+i -> (ic,ky,kx) in g_lds
    int off1[8];
    #pragma unroll
    for (int i = 0; i < 8; ++i) {
        const int k = 8 * q + i;
        if (k < 27) {
            const int ic = k / 9, r9 = k - ic * 9;
            const int ky = r9 / 3, kx = r9 - ky * 3;
            off1[i] = ic * (GT * GP) + ky * GP + kx;
        } else off1[i] = -1;
    }

    __syncthreads();

    const float* gb0 = &g_lds[0][0][0];
    const float* fb0p = &f_lds[0][0][0];
    ushort* hsw_hi = &h_s[w][0][0][0];
    ushort* hsw_lo = &h_s[w][1][0][0];

    const float4v zero4 = {0.f, 0.f, 0.f, 0.f};

    // ================= 4 groups of 16 pixels per wave =================
    #pragma unroll
    for (int g = 0; g < 4; ++g) {
        const int py = w * 4 + g;              // tile row
        const int gbase = py * GP + c;

        // ---- B1 frag: guidance patch column for pixel (py,c) ----
        short8 b1h, b1l;
        #pragma unroll
        for (int i = 0; i < 8; ++i) {
            const float f = (off1[i] >= 0) ? gb0[off1[i] + gbase] : 0.f;
            ushort hi, lo; split_bf(f, hi, lo);
            b1h[i] = (short)hi; b1l[i] = (short)lo;
        }

        // ---- conv3x3 GEMM (split 3-term) ----
        float4v acc1[2];
        #pragma unroll
        for (int t = 0; t < 2; ++t) {
            float4v a = zero4;
            a = MFMA16(a1h[t], b1h, a);
            a = MFMA16(a1h[t], b1l, a);
            a = MFMA16(a1l[t], b1h, a);
            acc1[t] = a;
        }

        // ---- bias + ReLU, split, bounce through LDS into B2 layout ----
        #pragma unroll
        for (int t = 0; t < 2; ++t) {
            ushort hi4[4], lo4[4];
            #pragma unroll
            for (int r = 0; r < 4; ++r) {
                const float hv = fmaxf(acc1[t][r] + b1v[t * 4 + r], 0.f);
                split_bf(hv, hi4[r], lo4[r]);
            }
            uint2 ph, pl;
            ph.x = (uint)hi4[0] | ((uint)hi4[1] << 16);
            ph.y = (uint)hi4[2] | ((uint)hi4[3] << 16);
            pl.x = (uint)lo4[0] | ((uint)lo4[1] << 16);
            pl.y = (uint)lo4[2] | ((uint)lo4[3] << 16);
            const int eoff = c * 40 + 16 * t + 4 * q;
            *reinterpret_cast<uint2*>(hsw_hi + eoff) = ph;
            *reinterpret_cast<uint2*>(hsw_lo + eoff) = pl;
        }

        // ---- read B2 frags (within-wave exchange; DS ops are in-order) ----
        const int roff = c * 40 + 8 * q;
        const short8 b2h = *reinterpret_cast<const short8*>(hsw_hi + roff);
        const short8 b2l = *reinterpret_cast<const short8*>(hsw_lo + roff);

        // ---- conv1x1 GEMM (split 3-term) ----
        float4v acc2[4];
        #pragma unroll
        for (int mt = 0; mt < 4; ++mt) {
            float4v a = zero4;
            a = MFMA16(a2h[mt], b2h, a);
            a = MFMA16(a2h[mt], b2l, a);
            a = MFMA16(a2l[mt], b2h, a);
            acc2[mt] = a;
        }

        // ---- combine: refined[ch] = sum_k kern(k) * patch(k) ----
        float s0 = 0.f, s1 = 0.f;
        const float* fbp = fb0p + py * FP + c;
        #pragma unroll
        for (int j = 0; j < 16; ++j) {
            if (offv[j] >= 0) {
                const float kern  = acc2[j >> 2][j & 3] + b2v[j];
                const float patch = fbp[offv[j]];
                const float kp = kern * patch;
                const bool ch = (chmask >> j) & 1;
                s0 += ch ? 0.f : kp;
                s1 += ch ? kp : 0.f;
            }
        }
        s0 += __shfl_xor(s0, 16);
        s0 += __shfl_xor(s0, 32);
        s1 += __shfl_xor(s1, 16);
        s1 += __shfl_xor(s1, 32);

        if (q == 0) {
            const int y = by0 + py, x = bx0 + c;
            out[((size_t)b * 2 + 0) * HH * WW + y * WW + x] = s0;
            out[((size_t)b * 2 + 1) * HH * WW + y * WW + x] = s1;
        }
    }
}

extern "C" void kernel_launch(void* const* d_in, const int* in_sizes, int n_in,
                              void* d_out, int out_size, void* d_ws, size_t ws_size,
                              hipStream_t stream) {
    const float* v0 = (const float*)d_in[0];
    const float* v2 = (const float*)d_in[1];
    const float* w1 = (const float*)d_in[2];
    const float* b1 = (const float*)d_in[3];
    const float* w2 = (const float*)d_in[4];
    const float* b2 = (const float*)d_in[5];
    float* out = (float*)d_out;

    dim3 block(256, 1, 1);
    dim3 grid(WW / TS, HH / TS, BB);
    temporal_refine_kernel<<<grid, block, 0, stream>>>(v0, v2, w1, b1, w2, b2, out);
}

// Round 4
// 105.688 us; speedup vs baseline: 1.3340x; 1.3340x over previous
//
#include <hip/hip_runtime.h>
#include <hip/hip_bf16.h>
#include <math.h>

#define BB  8
#define HH  512
#define WW  512

#define TS 16
#define GT 18            // guidance tile with 1-px halo
#define GS 20            // g_pk row stride (u32)
#define FT 20            // flow tile with 2-px halo
#define FP 21            // f_lds row stride (f32)
#define HS 44            // h_s row stride (u32)
#define ZOFF (3*GT*GS)   // start of zero pad region in g_pk
#define ZPAD 320         // pad words: must cover max gbase (15*GS+15 = 315)

typedef __attribute__((ext_vector_type(8))) short  short8;
typedef __attribute__((ext_vector_type(4))) float  float4v;
typedef __attribute__((ext_vector_type(4))) int    int4v;
typedef __attribute__((ext_vector_type(4))) uint   uint4v;

#define MFMA16(a,b,c) __builtin_amdgcn_mfma_f32_16x16x32_bf16((a),(b),(c),0,0,0)

// ---------- RNE split (setup only; cost irrelevant) ----------
static __device__ __forceinline__ ushort f2bf_rne(float f) {
    uint u = __float_as_uint(f);
    u += 0x7fffu + ((u >> 16) & 1u);
    return (ushort)(u >> 16);
}
static __device__ __forceinline__ void split_rne(float f, ushort& hi, ushort& lo) {
    hi = f2bf_rne(f);
    float r = f - __uint_as_float((uint)hi << 16);
    lo = f2bf_rne(r);
}
// ---------- truncation split, packed (hot path, ~5 ops) ----------
static __device__ __forceinline__ uint pack_split(float f) {
    uint u  = __float_as_uint(f);
    uint hi = u & 0xFFFF0000u;
    float r = f - __uint_as_float(hi);          // exact residual
    return hi | (__float_as_uint(r) >> 16);
}

// ===================== setup: per-lane MFMA params -> ws =====================
// chunk layout (uint4 ws[chunk*64 + lane]):
//  0..1  a1h[t]   2..3  a1l[t]      (w1 as [32 oc][27 k] padded K=32)
//  4..7  a2h[mt]  8..11 a2l[mt]     (w2 channel-split: row'=32*ch + kk, pad 64)
// 12..13 acc1 bias init [t]         (b1 at C-layout rows)
// 14..17 acc2 bias init [mt]        (b2 or 0)
// 18..21 offv int4 [mt]             (patch gather offsets, f32 units)
// 22..23 off1 int4 [half]           (guidance gather offsets, u32 units)
__global__ __launch_bounds__(64)
void setup_params(const float* __restrict__ w1, const float* __restrict__ b1,
                  const float* __restrict__ w2, const float* __restrict__ b2,
                  uint4v* __restrict__ ws)
{
    const int L = threadIdx.x;
    const int c = L & 15, q = L >> 4;

    #pragma unroll
    for (int t = 0; t < 2; ++t) {
        short8 hi8, lo8;
        #pragma unroll
        for (int i = 0; i < 8; ++i) {
            const int k = 8 * q + i;
            const float f = (k < 27) ? w1[(16 * t + c) * 27 + k] : 0.f;
            ushort h_, l_; split_rne(f, h_, l_);
            hi8[i] = (short)h_; lo8[i] = (short)l_;
        }
        *reinterpret_cast<short8*>(&ws[(0 + t) * 64 + L]) = hi8;
        *reinterpret_cast<short8*>(&ws[(2 + t) * 64 + L]) = lo8;
    }
    #pragma unroll
    for (int mt = 0; mt < 4; ++mt) {
        const int ch = mt >> 1;
        const int kk = 16 * (mt & 1) + c;       // kernel tap index of this row
        short8 hi8, lo8;
        #pragma unroll
        for (int i = 0; i < 8; ++i) {
            const float f = (kk < 25) ? w2[(25 * ch + kk) * 32 + 8 * q + i] : 0.f;
            ushort h_, l_; split_rne(f, h_, l_);
            hi8[i] = (short)h_; lo8[i] = (short)l_;
        }
        *reinterpret_cast<short8*>(&ws[(4 + mt) * 64 + L]) = hi8;
        *reinterpret_cast<short8*>(&ws[(8 + mt) * 64 + L]) = lo8;
    }
    #pragma unroll
    for (int t = 0; t < 2; ++t) {
        float4v v;
        #pragma unroll
        for (int r = 0; r < 4; ++r) v[r] = b1[16 * t + 4 * q + r];
        *reinterpret_cast<float4v*>(&ws[(12 + t) * 64 + L]) = v;
    }
    #pragma unroll
    for (int mt = 0; mt < 4; ++mt) {
        const int ch = mt >> 1;
        float4v v; int4v o;
        #pragma unroll
        for (int r = 0; r < 4; ++r) {
            const int kk = 16 * (mt & 1) + 4 * q + r;
            if (kk < 25) {
                v[r] = b2[25 * ch + kk];
                o[r] = ch * (FT * FP) + (kk / 5) * FP + (kk % 5);
            } else { v[r] = 0.f; o[r] = 0; }
        }
        *reinterpret_cast<float4v*>(&ws[(14 + mt) * 64 + L]) = v;
        *reinterpret_cast<int4v*>(&ws[(18 + mt) * 64 + L]) = o;
    }
    #pragma unroll
    for (int hf = 0; hf < 2; ++hf) {
        int4v o;
        #pragma unroll
        for (int i2 = 0; i2 < 4; ++i2) {
            const int k = 8 * q + 4 * hf + i2;
            if (k < 27) {
                const int ic = k / 9, r9 = k - ic * 9;
                o[i2] = ic * (GT * GS) + (r9 / 3) * GS + (r9 % 3);
            } else o[i2] = ZOFF;                // zero pad region (covers +gbase)
        }
        *reinterpret_cast<int4v*>(&ws[(22 + hf) * 64 + L]) = o;
    }
}

// ============================== main kernel ==============================
__global__ __launch_bounds__(256)
void temporal_refine_kernel(const float* __restrict__ v0,
                            const float* __restrict__ v2,
                            const uint4v* __restrict__ P,
                            float* __restrict__ out)
{
    __shared__ uint  g_pk[3 * GT * GS + ZPAD];  // packed (bf16hi<<16)|bf16lo
    __shared__ float f_lds[2 * FT * FP];
    __shared__ uint  h_s[4 * 16 * HS];          // per-wave packed h bounce

    const int bx0 = blockIdx.x * TS;
    const int by0 = blockIdx.y * TS;
    const int b   = blockIdx.z;
    const int tid = threadIdx.x;
    const int w   = tid >> 6;
    const int L   = tid & 63;
    const int c   = L & 15;
    const int q   = L >> 4;

    const float* v0b = v0 + (size_t)b * 2 * HH * WW;
    const float* v2b = v2 + (size_t)b * 2 * HH * WW;

    // ---- per-lane params (coalesced, L2-resident) ----
    short8 a1h[2], a1l[2], a2h[4], a2l[4];
    #pragma unroll
    for (int t = 0; t < 2; ++t) {
        a1h[t] = *reinterpret_cast<const short8*>(&P[(0 + t) * 64 + L]);
        a1l[t] = *reinterpret_cast<const short8*>(&P[(2 + t) * 64 + L]);
    }
    #pragma unroll
    for (int mt = 0; mt < 4; ++mt) {
        a2h[mt] = *reinterpret_cast<const short8*>(&P[(4 + mt) * 64 + L]);
        a2l[mt] = *reinterpret_cast<const short8*>(&P[(8 + mt) * 64 + L]);
    }
    float4v bi1[2], bi2[4];
    #pragma unroll
    for (int t = 0; t < 2; ++t)
        bi1[t] = *reinterpret_cast<const float4v*>(&P[(12 + t) * 64 + L]);
    #pragma unroll
    for (int mt = 0; mt < 4; ++mt)
        bi2[mt] = *reinterpret_cast<const float4v*>(&P[(14 + mt) * 64 + L]);
    int offv[16], off1[8];
    #pragma unroll
    for (int mt = 0; mt < 4; ++mt) {
        const int4v o = *reinterpret_cast<const int4v*>(&P[(18 + mt) * 64 + L]);
        #pragma unroll
        for (int r = 0; r < 4; ++r) offv[mt * 4 + r] = o[r];
    }
    #pragma unroll
    for (int hf = 0; hf < 2; ++hf) {
        const int4v o = *reinterpret_cast<const int4v*>(&P[(22 + hf) * 64 + L]);
        #pragma unroll
        for (int i2 = 0; i2 < 4; ++i2) off1[hf * 4 + i2] = o[i2];
    }

    // ---- stage guidance (halo 1), pre-split to packed bf16 hi|lo ----
    for (int i = tid; i < GT * GT; i += 256) {
        const int ly = i / GT, lx = i - ly * GT;
        const int y = by0 - 1 + ly, x = bx0 - 1 + lx;
        float fb0 = 0.f, fb1 = 0.f, wv = 0.f;
        if (y >= 0 && y < HH && x >= 0 && x < WW) {
            const float f0 = v0b[y * WW + x];
            const float f1 = v0b[HH * WW + y * WW + x];
            const float sgx = (-1.0f + x * (2.0f / (WW - 1))) + f0 * (2.0f / WW);
            const float sgy = (-1.0f + y * (2.0f / (HH - 1))) + f1 * (2.0f / HH);
            const float ixf = (sgx + 1.0f) * (0.5f * (WW - 1));
            const float iyf = (sgy + 1.0f) * (0.5f * (HH - 1));
            const float x0f = floorf(ixf), y0f = floorf(iyf);
            const int   x0  = (int)x0f,   y0i = (int)y0f;
            const float wx1 = ixf - x0f, wx0 = 1.0f - wx1;
            const float wy1 = iyf - y0f, wy0 = 1.0f - wy1;
            float s0 = 0.f, s1 = 0.f;
            #pragma unroll
            for (int cy = 0; cy < 2; ++cy) {
                const int yy = y0i + cy;
                const float wy = cy ? wy1 : wy0;
                if (yy >= 0 && yy < HH) {
                    #pragma unroll
                    for (int cx = 0; cx < 2; ++cx) {
                        const int xx = x0 + cx;
                        if (xx >= 0 && xx < WW) {
                            const float wgt = wy * (cx ? wx1 : wx0);
                            const int idx = yy * WW + xx;
                            s0 = fmaf(wgt, v2b[idx], s0);
                            s1 = fmaf(wgt, v2b[HH * WW + idx], s1);
                        }
                    }
                }
            }
            fb0 = f0 + s0;
            fb1 = f1 + s1;
            wv  = __expf(-sqrtf(fmaf(fb0, fb0, fb1 * fb1)));
        }
        g_pk[0 * GT * GS + ly * GS + lx] = pack_split(fb0);
        g_pk[1 * GT * GS + ly * GS + lx] = pack_split(fb1);
        g_pk[2 * GT * GS + ly * GS + lx] = pack_split(wv);
    }
    // zero pad region: off1 pad entries read g_pk[ZOFF + gbase], gbase <= 315
    for (int i = tid; i < ZPAD; i += 256) g_pk[ZOFF + i] = 0u;

    // ---- stage flow (halo 2) ----
    for (int i = tid; i < FT * FT; i += 256) {
        const int ly = i / FT, lx = i - ly * FT;
        const int y = by0 - 2 + ly, x = bx0 - 2 + lx;
        float f0 = 0.f, f1 = 0.f;
        if (y >= 0 && y < HH && x >= 0 && x < WW) {
            f0 = v0b[y * WW + x];
            f1 = v0b[HH * WW + y * WW + x];
        }
        f_lds[0 * FT * FP + ly * FP + lx] = f0;
        f_lds[1 * FT * FP + ly * FP + lx] = f1;
    }
    __syncthreads();

    uint* hw = h_s + w * (16 * HS);

    #pragma unroll
    for (int g = 0; g < 4; ++g) {
        const int py = w * 4 + g;
        const int gbase = py * GS + c;

        // B1 frag: 8 packed reads + unpack
        uint u[8];
        #pragma unroll
        for (int i = 0; i < 8; ++i) u[i] = g_pk[off1[i] + gbase];
        short8 b1h, b1l;
        #pragma unroll
        for (int i = 0; i < 8; ++i) {
            b1h[i] = (short)(u[i] >> 16);
            b1l[i] = (short)(u[i] & 0xFFFFu);
        }

        // conv3x3 GEMM, bias pre-loaded in C
        float4v acc1[2] = {bi1[0], bi1[1]};
        #pragma unroll
        for (int t = 0; t < 2; ++t) {
            acc1[t] = MFMA16(a1h[t], b1h, acc1[t]);
            acc1[t] = MFMA16(a1h[t], b1l, acc1[t]);
            acc1[t] = MFMA16(a1l[t], b1h, acc1[t]);
        }

        // ReLU + packed split -> LDS bounce (C-layout -> B-layout)
        #pragma unroll
        for (int t = 0; t < 2; ++t) {
            uint4v pk;
            #pragma unroll
            for (int r = 0; r < 4; ++r)
                pk[r] = pack_split(fmaxf(acc1[t][r], 0.f));
            *reinterpret_cast<uint4v*>(&hw[c * HS + 16 * t + 4 * q]) = pk;
        }
        const uint4v r0 = *reinterpret_cast<const uint4v*>(&hw[c * HS + 8 * q]);
        const uint4v r1 = *reinterpret_cast<const uint4v*>(&hw[c * HS + 8 * q + 4]);
        short8 b2h, b2l;
        #pragma unroll
        for (int i = 0; i < 4; ++i) {
            b2h[i]     = (short)(r0[i] >> 16);
            b2l[i]     = (short)(r0[i] & 0xFFFFu);
            b2h[4 + i] = (short)(r1[i] >> 16);
            b2l[4 + i] = (short)(r1[i] & 0xFFFFu);
        }

        // conv1x1 GEMM, bias pre-loaded in C
        float4v acc2[4] = {bi2[0], bi2[1], bi2[2], bi2[3]};
        #pragma unroll
        for (int mt = 0; mt < 4; ++mt) {
            acc2[mt] = MFMA16(a2h[mt], b2h, acc2[mt]);
            acc2[mt] = MFMA16(a2h[mt], b2l, acc2[mt]);
            acc2[mt] = MFMA16(a2l[mt], b2h, acc2[mt]);
        }

        // combine: kern already includes bias; dead rows have kern == 0
        const float* fbase = f_lds + py * FP + c;
        float s0 = 0.f, s1 = 0.f;
        #pragma unroll
        for (int j = 0; j < 16; ++j) {
            const float patch = fbase[offv[j]];
            const float kern  = acc2[j >> 2][j & 3];
            if (j < 8) s0 = fmaf(kern, patch, s0);
            else       s1 = fmaf(kern, patch, s1);
        }
        s0 += __shfl_xor(s0, 16);
        s0 += __shfl_xor(s0, 32);
        s1 += __shfl_xor(s1, 16);
        s1 += __shfl_xor(s1, 32);

        if (q == 0) {
            const int y = by0 + py, x = bx0 + c;
            out[((size_t)b * 2 + 0) * HH * WW + y * WW + x] = s0;
            out[((size_t)b * 2 + 1) * HH * WW + y * WW + x] = s1;
        }
    }
}

extern "C" void kernel_launch(void* const* d_in, const int* in_sizes, int n_in,
                              void* d_out, int out_size, void* d_ws, size_t ws_size,
                              hipStream_t stream) {
    const float* v0 = (const float*)d_in[0];
    const float* v2 = (const float*)d_in[1];
    const float* w1 = (const float*)d_in[2];
    const float* b1 = (const float*)d_in[3];
    const float* w2 = (const float*)d_in[4];
    const float* b2 = (const float*)d_in[5];
    uint4v* ws = (uint4v*)d_ws;

    setup_params<<<1, 64, 0, stream>>>(w1, b1, w2, b2, ws);

    dim3 grid(WW / TS, HH / TS, BB);
    temporal_refine_kernel<<<grid, dim3(256, 1, 1), 0, stream>>>(v0, v2, ws, (float*)d_out);
}